// Round 1
// baseline (483.481 us; speedup 1.0000x reference)
//
#include <hip/hip_runtime.h>

#define BB 16
#define RR 64
#define SS 128
#define MM 64
#define LL 128
#define EE 4032

// out layout (fp32, concatenated):
// inc_add [16*64*128 = 131072] | inc_gain [131072] |
// mean_s [16*64*64*64 = 4194304] | logstd_s [4194304] | msg_s [4194304]
#define OUT3_OFF 262144
#define ARR_SZ   4194304

// ---------------------------------------------------------------------------
// Zero the scatter-add targets and the diagonal (s==t) blocks of the three
// scattered outputs (d_out is re-poisoned to 0xAA before every launch).
// 262144 + 3*65536 = 458752 elements -> 1792 blocks x 256 exactly.
// ---------------------------------------------------------------------------
__global__ __launch_bounds__(256) void k_zero(float* __restrict__ out) {
  int tid = blockIdx.x * 256 + threadIdx.x;
  if (tid < 262144) { out[tid] = 0.0f; return; }
  int idx = tid - 262144;          // < 196608
  int a = idx >> 16;               // which of the 3 scattered arrays
  int r = idx & 65535;
  int b = r >> 12;                 // batch
  int d = (r >> 6) & 63;           // diagonal index
  int m = r & 63;
  out[OUT3_OFF + (size_t)a * ARR_SZ + (size_t)b * 262144 + d * 4160 + m] = 0.0f;
}

// ---------------------------------------------------------------------------
// One block per edge: mean/logstd GEMMs + scatter-set of mean/logstd/msg.
// Thread t: m = t>>2, sq = t&3 (s-quarter, interleaved 16-float strips so
// LDS reads are conflict-free broadcasts with src row stride 132).
// ---------------------------------------------------------------------------
__global__ __launch_bounds__(256) void k_edge(
    const float* __restrict__ source,
    const float* __restrict__ mean_w,
    const float* __restrict__ mean_b,
    const float* __restrict__ logstd_w,
    const float* __restrict__ logstd_b,
    const int* __restrict__ src_idx,
    const int* __restrict__ tgt_idx,
    float* __restrict__ out)
{
  __shared__ float lds_src[BB * 132];     // 16 rows of 128, stride 132
  __shared__ float lds_mean[BB * 64];
  __shared__ float lds_logstd[BB * 64];
  const int e = blockIdx.x;
  const int tid = threadIdx.x;
  const int sidx = src_idx[e];
  const int tidx = tgt_idx[e];

  // stage source[:, sidx, :] (16 x 128 floats = 512 float4)
  #pragma unroll
  for (int f0 = 0; f0 < 2; ++f0) {
    int f = tid + f0 * 256;
    int b = f >> 5, s4 = f & 31;
    float4 v = *(const float4*)(source + ((size_t)b * (RR * SS) + (size_t)sidx * SS + s4 * 4));
    *(float4*)(lds_src + b * 132 + s4 * 4) = v;
  }
  __syncthreads();

  const int m = tid >> 2;   // 0..63
  const int sq = tid & 3;   // s-quarter
  float accm[BB], accl[BB];
  #pragma unroll
  for (int b = 0; b < BB; ++b) { accm[b] = 0.0f; accl[b] = 0.0f; }

  const float* wmp = mean_w   + ((size_t)e * (MM * SS) + (size_t)m * SS);
  const float* wlp = logstd_w + ((size_t)e * (MM * SS) + (size_t)m * SS);
  #pragma unroll
  for (int k = 0; k < 8; ++k) {
    const int soff = sq * 4 + k * 16;   // interleaved strips: conflict-free LDS
    float4 a = *(const float4*)(wmp + soff);
    float4 c = *(const float4*)(wlp + soff);
    #pragma unroll
    for (int b = 0; b < BB; ++b) {
      float4 sv = *(const float4*)(lds_src + b * 132 + soff);
      accm[b] = fmaf(a.x, sv.x, fmaf(a.y, sv.y, fmaf(a.z, sv.z, fmaf(a.w, sv.w, accm[b]))));
      accl[b] = fmaf(c.x, sv.x, fmaf(c.y, sv.y, fmaf(c.z, sv.z, fmaf(c.w, sv.w, accl[b]))));
    }
  }
  // reduce the 4 s-quarters (adjacent lanes) — all 4 lanes end with full sums
  #pragma unroll
  for (int b = 0; b < BB; ++b) {
    accm[b] += __shfl_xor(accm[b], 1);
    accm[b] += __shfl_xor(accm[b], 2);
    accl[b] += __shfl_xor(accl[b], 1);
    accl[b] += __shfl_xor(accl[b], 2);
  }
  const float bm = mean_b[e * MM + m];
  const float bl = logstd_b[e * MM + m];
  #pragma unroll
  for (int j = 0; j < 4; ++j) {
    int b = sq * 4 + j;                 // each lane writes 4 distinct batches
    lds_mean[b * 64 + m]   = accm[b] + bm;
    lds_logstd[b * 64 + m] = accl[b] + bl;
  }
  __syncthreads();

  // coalesced 256B-segment scatter-set writes: msg == mean (deterministic path)
  float* out3 = out + OUT3_OFF;
  float* out4 = out3 + ARR_SZ;
  float* out5 = out4 + ARR_SZ;
  const size_t rowbase = (size_t)(sidx * RR + tidx) * MM;
  const int b = tid >> 4, m4 = tid & 15;
  float4 vm = *(float4*)(lds_mean + b * 64 + m4 * 4);
  float4 vl = *(float4*)(lds_logstd + b * 64 + m4 * 4);
  size_t o = (size_t)b * (RR * RR * MM) + rowbase + m4 * 4;
  *(float4*)(out3 + o) = vm;
  *(float4*)(out4 + o) = vl;
  *(float4*)(out5 + o) = vm;
}

// ---------------------------------------------------------------------------
// Scatter-add stage: grid = 64 tgt x 2 l-halves x 9 s-chunks (7 edges each).
// Reads mean tiles back from out3 (16.5MB x2), streams add_w/gain_w once.
// Thread t: l_loc = t>>2, mq = t&3 (m-quarter of 16), register accumulate,
// shfl reduce, ~2.4M atomicAdds total (9 per destination address).
// ---------------------------------------------------------------------------
__global__ __launch_bounds__(256) void k_inc(
    const float* __restrict__ add_w,
    const float* __restrict__ gain_w,
    float* __restrict__ out)
{
  __shared__ float lds_mean[BB * 64];
  const int g = blockIdx.x;        // 64*2*9 = 1152
  const int tt = g / 18;
  const int r = g % 18;
  const int lh = r / 9;
  const int c = r % 9;
  const int tid = threadIdx.x;
  const int l_loc = tid >> 2;      // 0..63
  const int mq = tid & 3;          // m-quarter
  const int l = lh * 64 + l_loc;

  float acca[BB], accg[BB];
  #pragma unroll
  for (int b = 0; b < BB; ++b) { acca[b] = 0.0f; accg[b] = 0.0f; }

  const float* out3 = out + OUT3_OFF;
  for (int j = 0; j < 7; ++j) {
    const int si = c * 7 + j;                  // 0..62
    const int s = si + (si >= tt ? 1 : 0);     // skip s == tt
    const int e = s * 63 + (tt > s ? tt - 1 : tt);
    __syncthreads();                           // protect previous tile reads
    {
      int b = tid >> 4, m4 = tid & 15;
      *(float4*)(lds_mean + b * 64 + m4 * 4) =
          *(const float4*)(out3 + ((size_t)b * 262144 + (size_t)(s * 64 + tt) * 64 + m4 * 4));
    }
    __syncthreads();
    const float* wa = add_w  + ((size_t)e * (LL * MM) + (size_t)l * MM + mq * 16);
    const float* wg = gain_w + ((size_t)e * (LL * MM) + (size_t)l * MM + mq * 16);
    #pragma unroll
    for (int i = 0; i < 4; ++i) {
      float4 a  = *(const float4*)(wa + i * 4);
      float4 gq = *(const float4*)(wg + i * 4);
      #pragma unroll
      for (int b = 0; b < BB; ++b) {
        float4 mv = *(const float4*)(lds_mean + b * 64 + mq * 16 + i * 4);
        acca[b] = fmaf(a.x,  mv.x, fmaf(a.y,  mv.y, fmaf(a.z,  mv.z, fmaf(a.w,  mv.w, acca[b]))));
        accg[b] = fmaf(gq.x, mv.x, fmaf(gq.y, mv.y, fmaf(gq.z, mv.z, fmaf(gq.w, mv.w, accg[b]))));
      }
    }
  }
  // reduce the 4 m-quarters (adjacent lanes)
  #pragma unroll
  for (int b = 0; b < BB; ++b) {
    acca[b] += __shfl_xor(acca[b], 1);
    acca[b] += __shfl_xor(acca[b], 2);
    accg[b] += __shfl_xor(accg[b], 1);
    accg[b] += __shfl_xor(accg[b], 2);
  }
  float* inc_add  = out;
  float* inc_gain = out + 131072;
  #pragma unroll
  for (int jj = 0; jj < 4; ++jj) {
    int b = mq * 4 + jj;                      // each lane commits 4 batches
    size_t o = (size_t)b * (RR * LL) + (size_t)tt * LL + l;
    atomicAdd(inc_add + o, acca[b]);
    atomicAdd(inc_gain + o, accg[b]);
  }
}

extern "C" void kernel_launch(void* const* d_in, const int* in_sizes, int n_in,
                              void* d_out, int out_size, void* d_ws, size_t ws_size,
                              hipStream_t stream) {
  const float* source   = (const float*)d_in[0];
  const float* mean_w   = (const float*)d_in[1];
  const float* mean_b   = (const float*)d_in[2];
  const float* logstd_w = (const float*)d_in[3];
  const float* logstd_b = (const float*)d_in[4];
  const float* add_w    = (const float*)d_in[5];
  const float* gain_w   = (const float*)d_in[6];
  const int*   src_idx  = (const int*)d_in[7];
  const int*   tgt_idx  = (const int*)d_in[8];
  float* out = (float*)d_out;

  k_zero<<<1792, 256, 0, stream>>>(out);
  k_edge<<<EE, 256, 0, stream>>>(source, mean_w, mean_b, logstd_w, logstd_b,
                                 src_idx, tgt_idx, out);
  k_inc<<<1152, 256, 0, stream>>>(add_w, gain_w, out);
}